// Round 9
// baseline (148.806 us; speedup 1.0000x reference)
//
#include <hip/hip_runtime.h>
#include <hip/hip_bf16.h>
#include <stdint.h>
#include <math.h>

#define BM 128
#define BN 128
#define BK 64

typedef __attribute__((ext_vector_type(8))) short bf16x8;
typedef __attribute__((ext_vector_type(4))) float f32x4;
typedef unsigned short ushort_t;

__device__ inline unsigned short f2b(float f) {
  unsigned u = __float_as_uint(f);
  unsigned r = (u + 0x7FFFu + ((u >> 16) & 1u)) >> 16;   // RNE, finite inputs
  return (unsigned short)r;
}

__device__ inline void gload_lds16(const void* g, void* l) {
  __builtin_amdgcn_global_load_lds(
      (const __attribute__((address_space(1))) void*)g,
      (__attribute__((address_space(3))) void*)l, 16, 0, 0);
}

// ---------------- fused prep: f32->bf16 (emb + 3 weights), bias concat, rowsum zero ----------------
#define N_EMB 8388608L   // 8192*1024
#define N_W   1048576L   // 1024*1024 (per weight, = 1<<20)
__global__ __launch_bounds__(256) void prep_kernel(
    const float* __restrict__ emb, const float* __restrict__ Wq,
    const float* __restrict__ Wk, const float* __restrict__ Wv,
    const float* __restrict__ bq, const float* __restrict__ bk,
    const float* __restrict__ bv, ushort_t* __restrict__ embB,
    ushort_t* __restrict__ WB, float* __restrict__ bqkv,
    float* __restrict__ rowsum) {
  long gid = (long)blockIdx.x * blockDim.x + threadIdx.x;
  long stride = (long)gridDim.x * blockDim.x;
  const long tot4 = (N_EMB + 3 * N_W) >> 2;  // float4 count
  for (long i = gid; i < tot4; i += stride) {
    long e = i << 2;
    const float* src;
    ushort_t* dst;
    long off;
    if (e < N_EMB) {
      src = emb; dst = embB; off = e;
    } else {
      long wfl = e - N_EMB;
      int wi = (int)(wfl >> 20);          // /N_W
      off = wfl & (N_W - 1);
      src = wi == 0 ? Wq : (wi == 1 ? Wk : Wv);
      dst = WB + (long)wi * N_W;
    }
    float4 v = *(const float4*)(src + off);
    ushort4 o;
    o.x = f2b(v.x); o.y = f2b(v.y); o.z = f2b(v.z); o.w = f2b(v.w);
    *(ushort4*)(dst + off) = o;
  }
  if (blockIdx.x == 0) {
    for (int i = threadIdx.x; i < 1024; i += 256) {
      bqkv[i] = bq[i];
      bqkv[1024 + i] = bk[i];
      bqkv[2048 + i] = bv[i];
    }
  }
  if (blockIdx.x == 1) {
    for (int i = threadIdx.x; i < 8192; i += 256) rowsum[i] = 0.f;
  }
}

// ---------------- 128x128 GEMM  C = A @ B^T  (A:[M][K], B:[N][K], bf16) ----------------
// BK=64, XOR-swizzled LDS; 32 MFMA per barrier; ~3 blocks/CU.
// MODE 0: C bf16 = acc + bias[col]   (projection; 'rowsum' arg = bias, bz=0)
// MODE 1: P bf16 = exp(acc*scale) causal; rowsum atomics.  Grid x = 136 =
//         packed lower-triangle index per batch (8x17 bijective XCD-chunk swizzle).
template <int MODE>
__global__ __launch_bounds__(256, 3) void gemm_bt(
    const ushort_t* __restrict__ A, const ushort_t* __restrict__ B,
    void* __restrict__ Cv, float* __restrict__ rowsum,
    int M, int N, int K, int lda, int ldb, int ldc,
    long bsA, long bsB, long bsC, float scale) {
  int bx, by, bz = blockIdx.z;
  if (MODE == 1) {
    // bijective XCD chunk swizzle over 136 blocks, then triangle index -> (by,bx)
    int sw = (blockIdx.x & 7) * 17 + (blockIdx.x >> 3);
    int r = (int)floorf((sqrtf(8.0f * sw + 1.0f) - 1.0f) * 0.5f);
    while ((r + 1) * (r + 2) / 2 <= sw) ++r;
    while (r * (r + 1) / 2 > sw) --r;
    by = r;
    bx = sw - r * (r + 1) / 2;     // bx <= by guaranteed
  } else {
    bx = blockIdx.x;
    by = blockIdx.y;
  }

  const ushort_t* Ab = A + (size_t)bz * bsA + (size_t)by * BM * lda;
  const ushort_t* Bb = B + (size_t)bz * bsB + (size_t)bx * BN * ldb;

  __shared__ __align__(16) ushort_t As[BM * BK];  // 16 KiB
  __shared__ __align__(16) ushort_t Bs[BN * BK];  // 16 KiB

  int tid = threadIdx.x;
  int lane = tid & 63;
  int w = tid >> 6;                 // 4 waves
  int wm = w >> 1, wn = w & 1;

  f32x4 acc[4][4];
#pragma unroll
  for (int i = 0; i < 4; i++)
#pragma unroll
    for (int j = 0; j < 4; j++) acc[i][j] = (f32x4)(0.f);

  // staging: wave w covers rows w*32 .. w*32+31 (4 gload_lds of 8 rows each)
  int srow = lane >> 3;                      // 0..7 within 8-row group
  int scol = ((lane & 7) ^ srow) << 3;       // pre-swizzled source col (elems)
  int fr = lane & 15, g16 = (lane >> 4) * 16;

  int nk = K / BK;
  for (int kt = 0; kt < nk; ++kt) {
    const ushort_t* Abase = Ab + (size_t)(w * 32 + srow) * lda + kt * BK + scol;
    const ushort_t* Bbase = Bb + (size_t)(w * 32 + srow) * ldb + kt * BK + scol;
#pragma unroll
    for (int j = 0; j < 4; ++j) {
      gload_lds16(Abase + (size_t)(j * 8) * lda, &As[(w * 32 + j * 8) * BK]);
      gload_lds16(Bbase + (size_t)(j * 8) * ldb, &Bs[(w * 32 + j * 8) * BK]);
    }
    __syncthreads();

    bf16x8 af[4][2], bf[4][2];
#pragma unroll
    for (int i = 0; i < 4; i++)
#pragma unroll
      for (int ks = 0; ks < 2; ++ks) {
        int ra = wm * 64 + i * 16 + fr;
        af[i][ks] = *(const bf16x8*)((const char*)As + ra * 128 +
                                     ((ks * 64 + g16) ^ ((ra & 7) << 4)));
        int rb2 = wn * 64 + i * 16 + fr;
        bf[i][ks] = *(const bf16x8*)((const char*)Bs + rb2 * 128 +
                                     ((ks * 64 + g16) ^ ((rb2 & 7) << 4)));
      }
#pragma unroll
    for (int mi = 0; mi < 4; mi++)
#pragma unroll
      for (int ni = 0; ni < 4; ni++)
#pragma unroll
        for (int ks = 0; ks < 2; ++ks)
          acc[mi][ni] = __builtin_amdgcn_mfma_f32_16x16x32_bf16(
              af[mi][ks], bf[ni][ks], acc[mi][ni], 0, 0, 0);
    __syncthreads();
  }

  int c = lane & 15;
  int rb = (lane >> 4) * 4;
  if (MODE == 0) {
    ushort_t* Cp = (ushort_t*)Cv;
    float bv4[4];
#pragma unroll
    for (int ni = 0; ni < 4; ni++) bv4[ni] = rowsum[bx * BN + wn * 64 + ni * 16 + c];
#pragma unroll
    for (int mi = 0; mi < 4; mi++)
#pragma unroll
      for (int j = 0; j < 4; j++) {
        int row = by * BM + wm * 64 + mi * 16 + rb + j;
#pragma unroll
        for (int ni = 0; ni < 4; ni++) {
          int col = bx * BN + wn * 64 + ni * 16 + c;
          Cp[(size_t)row * ldc + col] = f2b(acc[mi][ni][j] + bv4[ni]);
        }
      }
  } else {
    ushort_t* Cp = (ushort_t*)Cv + (size_t)bz * bsC;
#pragma unroll
    for (int mi = 0; mi < 4; mi++)
#pragma unroll
      for (int j = 0; j < 4; j++) {
        int row = by * BM + wm * 64 + mi * 16 + rb + j;
        float rsum = 0.f;
#pragma unroll
        for (int ni = 0; ni < 4; ni++) {
          int col = bx * BN + wn * 64 + ni * 16 + c;
          float e = 0.f;
          if (bx != by || col <= row) e = __expf(acc[mi][ni][j] * scale);
          rsum += e;
          Cp[(size_t)row * ldc + col] = f2b(e);
        }
#pragma unroll
        for (int o = 1; o < 16; o <<= 1) rsum += __shfl_xor(rsum, o);
        if (c == 0) atomicAdd(&rowsum[(size_t)bz * M + row], rsum);
      }
  }
}

// ---------------- PV: out = (P @ Vt^T) / rowsum, 64x256 tiles ----------------
// P:[b][S][S] bf16 (unnormalized exp, zero above diagonal), Vt:[b][A][S] bf16.
// 64x256 tile halves P panel re-reads vs 128x128 (4 col-blocks instead of 8);
// Vt traffic unchanged (32 row-blocks x 256-wide panels == 16 x 128-wide).
// 4 waves as 1M x 4N: all waves share A-frags (broadcast ds_read).
// K capped at ((by>>1)+1)*128 (causal); flip remap for bz>=2 pairs co-resident
// blocks (i, i+256) so per-CU K-work is constant (17 units per pair).
__global__ __launch_bounds__(256, 3) void pv64x256(
    const ushort_t* __restrict__ P, const ushort_t* __restrict__ V,
    float* __restrict__ out, const float* __restrict__ rowsum) {
  const int S = 2048, A = 1024;
  int bx = blockIdx.x, bz = blockIdx.z;
  int by = (bz & 2) ? (31 - (int)blockIdx.y) : (int)blockIdx.y;

  const ushort_t* Ab = P + (size_t)bz * S * S + (size_t)by * 64 * S;
  const ushort_t* Bb = V + (size_t)bz * A * S + (size_t)bx * 256 * S;
  int Keff = ((by >> 1) + 1) * 128;

  __shared__ __align__(16) ushort_t As[64 * 64];    //  8 KiB
  __shared__ __align__(16) ushort_t Bs[256 * 64];   // 32 KiB

  int tid = threadIdx.x;
  int lane = tid & 63;
  int w = tid >> 6;                 // 4 waves, 1M x 4N

  f32x4 acc[4][4];
#pragma unroll
  for (int i = 0; i < 4; i++)
#pragma unroll
    for (int j = 0; j < 4; j++) acc[i][j] = (f32x4)(0.f);

  int srow = lane >> 3;                      // 0..7 within 8-row group
  int scol = ((lane & 7) ^ srow) << 3;       // pre-swizzled source col (elems)
  int fr = lane & 15, g16 = (lane >> 4) * 16;

  int nk = Keff / 64;
  for (int kt = 0; kt < nk; ++kt) {
    const ushort_t* Abase = Ab + (size_t)(w * 16 + srow) * S + kt * 64 + scol;
    const ushort_t* Bbase = Bb + (size_t)(w * 64 + srow) * S + kt * 64 + scol;
#pragma unroll
    for (int j = 0; j < 2; ++j)
      gload_lds16(Abase + (size_t)(j * 8) * S, &As[(w * 16 + j * 8) * 64]);
#pragma unroll
    for (int j = 0; j < 8; ++j)
      gload_lds16(Bbase + (size_t)(j * 8) * S, &Bs[(w * 64 + j * 8) * 64]);
    __syncthreads();

    bf16x8 af[4][2], bf[4][2];
#pragma unroll
    for (int i = 0; i < 4; i++)
#pragma unroll
      for (int ks = 0; ks < 2; ++ks) {
        int ra = i * 16 + fr;                          // rows 0..63 (shared)
        af[i][ks] = *(const bf16x8*)((const char*)As + ra * 128 +
                                     ((ks * 64 + g16) ^ ((ra & 7) << 4)));
        int rbv = w * 64 + i * 16 + fr;                // wave's 64-col group
        bf[i][ks] = *(const bf16x8*)((const char*)Bs + rbv * 128 +
                                     ((ks * 64 + g16) ^ ((rbv & 7) << 4)));
      }
#pragma unroll
    for (int mi = 0; mi < 4; mi++)
#pragma unroll
      for (int ni = 0; ni < 4; ni++)
#pragma unroll
        for (int ks = 0; ks < 2; ++ks)
          acc[mi][ni] = __builtin_amdgcn_mfma_f32_16x16x32_bf16(
              af[mi][ks], bf[ni][ks], acc[mi][ni], 0, 0, 0);
    __syncthreads();
  }

  int c = lane & 15;
  int rb = (lane >> 4) * 4;
  float* C = out + (size_t)bz * S * A;
#pragma unroll
  for (int mi = 0; mi < 4; mi++)
#pragma unroll
    for (int j = 0; j < 4; j++) {
      int row = by * 64 + mi * 16 + rb + j;
      float inv = 1.0f / rowsum[(size_t)bz * S + row];
#pragma unroll
      for (int ni = 0; ni < 4; ni++) {
        int col = bx * 256 + w * 64 + ni * 16 + c;
        C[(size_t)row * A + col] = acc[mi][ni][j] * inv;
      }
    }
}

// ---------------- bf16 transpose, 64x64 tiles (128B coalesced both sides) ----------------
__global__ __launch_bounds__(256) void transpose2d(const ushort_t* __restrict__ in,
                                                   ushort_t* __restrict__ out,
                                                   int rows, int cols, int ld_in,
                                                   long bs_in, long bs_out) {
  __shared__ ushort_t tile[64][66];
  int b = blockIdx.z;
  in += (size_t)b * bs_in;
  out += (size_t)b * bs_out;
  int c0 = blockIdx.x * 64, r0 = blockIdx.y * 64;
  int tx = threadIdx.x & 31, ty = threadIdx.x >> 5;
#pragma unroll
  for (int i = ty; i < 64; i += 8) {
    ushort2 v = *(const ushort2*)&in[(size_t)(r0 + i) * ld_in + c0 + 2 * tx];
    tile[i][2 * tx] = v.x;
    tile[i][2 * tx + 1] = v.y;
  }
  __syncthreads();
#pragma unroll
  for (int i = ty; i < 64; i += 8) {
    ushort2 o;
    o.x = tile[2 * tx][i];
    o.y = tile[2 * tx + 1][i];
    *(ushort2*)&out[(size_t)(c0 + i) * rows + r0 + 2 * tx] = o;
  }
}

extern "C" void kernel_launch(void* const* d_in, const int* in_sizes, int n_in,
                              void* d_out, int out_size, void* d_ws, size_t ws_size,
                              hipStream_t stream) {
  const int Bb = 4, S = 2048, E = 1024, A = 1024;
  const int N3 = 3 * A;             // fused projection width 3072
  const size_t M = (size_t)Bb * S;  // 8192
  const float* emb = (const float*)d_in[0];
  const float* Wq = (const float*)d_in[1];
  const float* bq = (const float*)d_in[2];
  const float* Wk = (const float*)d_in[3];
  const float* bk = (const float*)d_in[4];
  const float* Wv = (const float*)d_in[5];
  const float* bv = (const float*)d_in[6];
  float* out = (float*)d_out;

  char* ws = (char*)d_ws;
  // layout (byte offsets):
  ushort_t* QKV  = (ushort_t*)(ws + 0);           // 48 MiB [8192][3072]: Q|K|V
  ushort_t* Vt   = (ushort_t*)(ws + 50331648);    // 16 MiB [b][A][S]
  ushort_t* P    = (ushort_t*)(ws + 67108864);    // 32 MiB [b][S][S] bf16 (unnormalized exp)
  float* rowsum  = (float*)(ws + 100663296);      // 32 KiB [b*S]
  ushort_t* embB = (ushort_t*)(ws + 100696064);   // 16 MiB
  ushort_t* WB   = (ushort_t*)(ws + 117473280);   // 6 MiB = Wq|Wk|Wv bf16 [3072][1024]
  float*    bqkv = (float*)(ws + 123764736);      // 12 KiB
  if (ws_size < 157286400ull) return;             // refuse to corrupt

  // fused prep: emb+weights f32->bf16, bias concat, rowsum zero (1 node)
  prep_kernel<<<2048, 256, 0, stream>>>(emb, Wq, Wk, Wv, bq, bk, bv,
                                        embB, WB, bqkv, rowsum);

  // fused QKV projection: M=8192, N=3072, K=1024 -> 24x64 = 1536 blocks, ~3/CU
  gemm_bt<0><<<dim3(N3 / BN, M / BM, 1), dim3(256), 0, stream>>>(
      embB, WB, QKV, bqkv, (int)M, N3, E, E, E, N3, 0, 0, 0, 1.f);

  // V (cols 2048..3071 of QKV, ld 3072) -> Vt [A][S] per batch
  transpose2d<<<dim3(A / 64, S / 64, Bb), dim3(256), 0, stream>>>(
      QKV + 2 * A, Vt, S, A, N3, (long)S * N3, (long)A * S);

  // scores: packed lower-triangle grid, 136 = 8*17 blocks per batch
  gemm_bt<1><<<dim3(136, 1, Bb), dim3(256), 0, stream>>>(
      QKV /*Q*/, QKV + A /*K*/, P, rowsum, S, S, E, N3, N3, S,
      (long)S * N3, (long)S * N3, (long)S * S, 0.03125f);

  // PV: 64x256 tiles, K-balanced flip remap, divide by rowsum
  pv64x256<<<dim3(A / 256, S / 64, Bb), dim3(256), 0, stream>>>(
      P, Vt, out, rowsum);
}

// Round 10
// 138.748 us; speedup vs baseline: 1.0725x; 1.0725x over previous
//
#include <hip/hip_runtime.h>
#include <hip/hip_bf16.h>
#include <stdint.h>
#include <math.h>

#define BM 128
#define BN 128
#define BK 64

typedef __attribute__((ext_vector_type(8))) short bf16x8;
typedef __attribute__((ext_vector_type(4))) float f32x4;
typedef unsigned short ushort_t;

__device__ inline unsigned short f2b(float f) {
  unsigned u = __float_as_uint(f);
  unsigned r = (u + 0x7FFFu + ((u >> 16) & 1u)) >> 16;   // RNE, finite inputs
  return (unsigned short)r;
}

__device__ inline void gload_lds16(const void* g, void* l) {
  __builtin_amdgcn_global_load_lds(
      (const __attribute__((address_space(1))) void*)g,
      (__attribute__((address_space(3))) void*)l, 16, 0, 0);
}

// ---------------- fused prep: f32->bf16 (emb + 3 weights), bias concat, rowsum zero ----------------
#define N_EMB 8388608L   // 8192*1024
#define N_W   1048576L   // 1024*1024 (per weight, = 1<<20)
__global__ __launch_bounds__(256) void prep_kernel(
    const float* __restrict__ emb, const float* __restrict__ Wq,
    const float* __restrict__ Wk, const float* __restrict__ Wv,
    const float* __restrict__ bq, const float* __restrict__ bk,
    const float* __restrict__ bv, ushort_t* __restrict__ embB,
    ushort_t* __restrict__ WB, float* __restrict__ bqkv,
    float* __restrict__ rowsum) {
  long gid = (long)blockIdx.x * blockDim.x + threadIdx.x;
  long stride = (long)gridDim.x * blockDim.x;
  const long tot4 = (N_EMB + 3 * N_W) >> 2;  // float4 count
  for (long i = gid; i < tot4; i += stride) {
    long e = i << 2;
    const float* src;
    ushort_t* dst;
    long off;
    if (e < N_EMB) {
      src = emb; dst = embB; off = e;
    } else {
      long wfl = e - N_EMB;
      int wi = (int)(wfl >> 20);          // /N_W
      off = wfl & (N_W - 1);
      src = wi == 0 ? Wq : (wi == 1 ? Wk : Wv);
      dst = WB + (long)wi * N_W;
    }
    float4 v = *(const float4*)(src + off);
    ushort4 o;
    o.x = f2b(v.x); o.y = f2b(v.y); o.z = f2b(v.z); o.w = f2b(v.w);
    *(ushort4*)(dst + off) = o;
  }
  if (blockIdx.x == 0) {
    for (int i = threadIdx.x; i < 1024; i += 256) {
      bqkv[i] = bq[i];
      bqkv[1024 + i] = bk[i];
      bqkv[2048 + i] = bv[i];
    }
  }
  if (blockIdx.x == 1) {
    for (int i = threadIdx.x; i < 8192; i += 256) rowsum[i] = 0.f;
  }
}

// ---------------- 128x128 GEMM  C = A @ B^T  (A:[M][K], B:[N][K], bf16) ----------------
// BK=64, XOR-swizzled LDS; 32 MFMA per barrier; ~3 blocks/CU.
// MODE 0: projection. cols <2048 -> C bf16 = acc + bias[col] into QKV.
//         cols >=2048 (V third) -> TRANSPOSED write into Vt[b][a][s] via an
//         LDS re-tile (reuses the 32KB staging buffer = one 128x128 bf16 tile,
//         XOR swizzle keeps both directions <=2-way) -- replaces the standalone
//         transpose2d kernel (saves 32MB HBM + a launch).
// MODE 1: P bf16 = exp(acc*scale) causal; rowsum atomics.  Grid x = 136 =
//         packed lower-triangle index per batch (8x17 bijective XCD-chunk swizzle).
// MODE 2: C f32  = acc / rowsum[row], K capped at (by+1)*BM (PV).
//         Flip remap for bz>=2 balances co-resident K-caps (constant 17/pair).
template <int MODE>
__global__ __launch_bounds__(256, 3) void gemm_bt(
    const ushort_t* __restrict__ A, const ushort_t* __restrict__ B,
    void* __restrict__ Cv, float* __restrict__ rowsum,
    int M, int N, int K, int lda, int ldb, int ldc,
    long bsA, long bsB, long bsC, float scale, ushort_t* __restrict__ VtOut) {
  int bx, by, bz = blockIdx.z;
  if (MODE == 1) {
    // bijective XCD chunk swizzle over 136 blocks, then triangle index -> (by,bx)
    int sw = (blockIdx.x & 7) * 17 + (blockIdx.x >> 3);
    int r = (int)floorf((sqrtf(8.0f * sw + 1.0f) - 1.0f) * 0.5f);
    while ((r + 1) * (r + 2) / 2 <= sw) ++r;
    while (r * (r + 1) / 2 > sw) --r;
    by = r;
    bx = sw - r * (r + 1) / 2;     // bx <= by guaranteed
  } else if (MODE == 2) {
    bx = blockIdx.x;
    by = (bz & 2) ? ((int)gridDim.y - 1 - (int)blockIdx.y) : (int)blockIdx.y;
  } else {
    bx = blockIdx.x;
    by = blockIdx.y;
  }

  const ushort_t* Ab = A + (size_t)bz * bsA + (size_t)by * BM * lda;
  const ushort_t* Bb = B + (size_t)bz * bsB + (size_t)bx * BN * ldb;

  int Keff = K;
  if (MODE == 2) { int cap = (by + 1) * BM; Keff = cap < K ? cap : K; }

  __shared__ __align__(16) ushort_t sh[BM * BK + BN * BK];  // 32 KiB
  ushort_t* As = sh;
  ushort_t* Bs = sh + BM * BK;

  int tid = threadIdx.x;
  int lane = tid & 63;
  int w = tid >> 6;                 // 4 waves
  int wm = w >> 1, wn = w & 1;

  f32x4 acc[4][4];
#pragma unroll
  for (int i = 0; i < 4; i++)
#pragma unroll
    for (int j = 0; j < 4; j++) acc[i][j] = (f32x4)(0.f);

  // staging: wave w covers rows w*32 .. w*32+31 (4 gload_lds of 8 rows each)
  int srow = lane >> 3;                      // 0..7 within 8-row group
  int scol = ((lane & 7) ^ srow) << 3;       // pre-swizzled source col (elems)
  int fr = lane & 15, g16 = (lane >> 4) * 16;

  int nk = Keff / BK;
  for (int kt = 0; kt < nk; ++kt) {
    const ushort_t* Abase = Ab + (size_t)(w * 32 + srow) * lda + kt * BK + scol;
    const ushort_t* Bbase = Bb + (size_t)(w * 32 + srow) * ldb + kt * BK + scol;
#pragma unroll
    for (int j = 0; j < 4; ++j) {
      gload_lds16(Abase + (size_t)(j * 8) * lda, &As[(w * 32 + j * 8) * BK]);
      gload_lds16(Bbase + (size_t)(j * 8) * ldb, &Bs[(w * 32 + j * 8) * BK]);
    }
    __syncthreads();

    bf16x8 af[4][2], bf[4][2];
#pragma unroll
    for (int i = 0; i < 4; i++)
#pragma unroll
      for (int ks = 0; ks < 2; ++ks) {
        int ra = wm * 64 + i * 16 + fr;
        af[i][ks] = *(const bf16x8*)((const char*)As + ra * 128 +
                                     ((ks * 64 + g16) ^ ((ra & 7) << 4)));
        int rb2 = wn * 64 + i * 16 + fr;
        bf[i][ks] = *(const bf16x8*)((const char*)Bs + rb2 * 128 +
                                     ((ks * 64 + g16) ^ ((rb2 & 7) << 4)));
      }
#pragma unroll
    for (int mi = 0; mi < 4; mi++)
#pragma unroll
      for (int ni = 0; ni < 4; ni++)
#pragma unroll
        for (int ks = 0; ks < 2; ++ks)
          acc[mi][ni] = __builtin_amdgcn_mfma_f32_16x16x32_bf16(
              af[mi][ks], bf[ni][ks], acc[mi][ni], 0, 0, 0);
    __syncthreads();
  }

  int c = lane & 15;
  int rb = (lane >> 4) * 4;
  if (MODE == 0) {
    float bv4[4];
#pragma unroll
    for (int ni = 0; ni < 4; ni++) bv4[ni] = rowsum[bx * BN + wn * 64 + ni * 16 + c];
    if (bx < 16) {
      // Q|K thirds: normal row-major write into QKV
      ushort_t* Cp = (ushort_t*)Cv;
#pragma unroll
      for (int mi = 0; mi < 4; mi++)
#pragma unroll
        for (int j = 0; j < 4; j++) {
          int row = by * BM + wm * 64 + mi * 16 + rb + j;
#pragma unroll
          for (int ni = 0; ni < 4; ni++) {
            int col = bx * BN + wn * 64 + ni * 16 + c;
            Cp[(size_t)row * ldc + col] = f2b(acc[mi][ni][j] + bv4[ni]);
          }
        }
    } else {
      // V third: transpose via LDS, write Vt[b][a][s] coalesced.
      // tile byte addr: a_local*256 + ((s_local*2) ^ ((a_local&7)<<4))
      char* T = (char*)sh;
#pragma unroll
      for (int mi = 0; mi < 4; mi++)
#pragma unroll
        for (int j = 0; j < 4; j++) {
          int sl = wm * 64 + mi * 16 + rb + j;
#pragma unroll
          for (int ni = 0; ni < 4; ni++) {
            int al = wn * 64 + ni * 16 + c;
            *(ushort_t*)(T + al * 256 + ((sl * 2) ^ ((al & 7) << 4))) =
                f2b(acc[mi][ni][j] + bv4[ni]);
          }
        }
      __syncthreads();
      int b_ = by >> 4;                     // batch
      int s0 = (by & 15) * BM;              // seq offset within batch
      int a0 = (bx - 16) * BN;              // attn-dim offset
      ushort_t* Vb = VtOut + (size_t)b_ * 1024 * 2048;
#pragma unroll
      for (int p = 0; p < 16; ++p) {
        int al = (tid >> 5) + p * 8;
        int sl4 = (tid & 31) * 4;           // 4 ushorts = 8B per lane
        ushort4 v4 = *(const ushort4*)(T + al * 256 + ((sl4 * 2) ^ ((al & 7) << 4)));
        *(ushort4*)(Vb + (size_t)(a0 + al) * 2048 + s0 + sl4) = v4;
      }
    }
  } else if (MODE == 1) {
    ushort_t* Cp = (ushort_t*)Cv + (size_t)bz * bsC;
#pragma unroll
    for (int mi = 0; mi < 4; mi++)
#pragma unroll
      for (int j = 0; j < 4; j++) {
        int row = by * BM + wm * 64 + mi * 16 + rb + j;
        float rsum = 0.f;
#pragma unroll
        for (int ni = 0; ni < 4; ni++) {
          int col = bx * BN + wn * 64 + ni * 16 + c;
          float e = 0.f;
          if (bx != by || col <= row) e = __expf(acc[mi][ni][j] * scale);
          rsum += e;
          Cp[(size_t)row * ldc + col] = f2b(e);
        }
#pragma unroll
        for (int o = 1; o < 16; o <<= 1) rsum += __shfl_xor(rsum, o);
        if (c == 0) atomicAdd(&rowsum[(size_t)bz * M + row], rsum);
      }
  } else {
    float* C = (float*)Cv + (size_t)bz * bsC;
#pragma unroll
    for (int mi = 0; mi < 4; mi++)
#pragma unroll
      for (int j = 0; j < 4; j++) {
        int row = by * BM + wm * 64 + mi * 16 + rb + j;
        float inv = 1.0f / rowsum[(size_t)bz * M + row];
#pragma unroll
        for (int ni = 0; ni < 4; ni++) {
          int col = bx * BN + wn * 64 + ni * 16 + c;
          C[(size_t)row * ldc + col] = acc[mi][ni][j] * inv;
        }
      }
  }
}

extern "C" void kernel_launch(void* const* d_in, const int* in_sizes, int n_in,
                              void* d_out, int out_size, void* d_ws, size_t ws_size,
                              hipStream_t stream) {
  const int Bb = 4, S = 2048, E = 1024, A = 1024;
  const int N3 = 3 * A;             // fused projection width 3072
  const size_t M = (size_t)Bb * S;  // 8192
  const float* emb = (const float*)d_in[0];
  const float* Wq = (const float*)d_in[1];
  const float* bq = (const float*)d_in[2];
  const float* Wk = (const float*)d_in[3];
  const float* bk = (const float*)d_in[4];
  const float* Wv = (const float*)d_in[5];
  const float* bv = (const float*)d_in[6];
  float* out = (float*)d_out;

  char* ws = (char*)d_ws;
  // layout (byte offsets):
  ushort_t* QKV  = (ushort_t*)(ws + 0);           // 48 MiB [8192][3072]: Q|K|(V unused)
  ushort_t* Vt   = (ushort_t*)(ws + 50331648);    // 16 MiB [b][A][S]
  ushort_t* P    = (ushort_t*)(ws + 67108864);    // 32 MiB [b][S][S] bf16 (unnormalized exp)
  float* rowsum  = (float*)(ws + 100663296);      // 32 KiB [b*S]
  ushort_t* embB = (ushort_t*)(ws + 100696064);   // 16 MiB
  ushort_t* WB   = (ushort_t*)(ws + 117473280);   // 6 MiB = Wq|Wk|Wv bf16 [3072][1024]
  float*    bqkv = (float*)(ws + 123764736);      // 12 KiB
  if (ws_size < 157286400ull) return;             // refuse to corrupt

  // fused prep: emb+weights f32->bf16, bias concat, rowsum zero (1 node)
  prep_kernel<<<2048, 256, 0, stream>>>(emb, Wq, Wk, Wv, bq, bk, bv,
                                        embB, WB, bqkv, rowsum);

  // fused QKV projection (V third written transposed into Vt; transpose2d gone)
  gemm_bt<0><<<dim3(N3 / BN, M / BM, 1), dim3(256), 0, stream>>>(
      embB, WB, QKV, bqkv, (int)M, N3, E, E, E, N3, 0, 0, 0, 1.f, Vt);

  // scores: packed lower-triangle grid, 136 = 8*17 blocks per batch
  gemm_bt<1><<<dim3(136, 1, Bb), dim3(256), 0, stream>>>(
      QKV /*Q*/, QKV + A /*K*/, P, rowsum, S, S, E, N3, N3, S,
      (long)S * N3, (long)S * N3, (long)S * S, 0.03125f, nullptr);

  // PV: per batch M=2048, N=1024, K=2048 (capped, flip-balanced), /rowsum
  gemm_bt<2><<<dim3(A / BN, S / BM, Bb), dim3(256), 0, stream>>>(
      P, Vt, out, rowsum, S, A, S, S, S, A,
      (long)S * S, (long)A * S, (long)S * A, 1.f, nullptr);
}

// Round 11
// 137.522 us; speedup vs baseline: 1.0821x; 1.0089x over previous
//
#include <hip/hip_runtime.h>
#include <hip/hip_bf16.h>
#include <stdint.h>
#include <math.h>

#define BM 128
#define BN 128
#define BK 64

typedef __attribute__((ext_vector_type(8))) short bf16x8;
typedef __attribute__((ext_vector_type(4))) float f32x4;
typedef unsigned short ushort_t;

__device__ inline unsigned short f2b(float f) {
  unsigned u = __float_as_uint(f);
  unsigned r = (u + 0x7FFFu + ((u >> 16) & 1u)) >> 16;   // RNE, finite inputs
  return (unsigned short)r;
}

__device__ inline void gload_lds16(const void* g, void* l) {
  __builtin_amdgcn_global_load_lds(
      (const __attribute__((address_space(1))) void*)g,
      (__attribute__((address_space(3))) void*)l, 16, 0, 0);
}

// ---------------- fused prep: f32->bf16 (emb + 3 weights), bias concat, rowsum zero ----------------
#define N_EMB 8388608L   // 8192*1024
#define N_W   1048576L   // 1024*1024 (per weight, = 1<<20)
__global__ __launch_bounds__(256) void prep_kernel(
    const float* __restrict__ emb, const float* __restrict__ Wq,
    const float* __restrict__ Wk, const float* __restrict__ Wv,
    const float* __restrict__ bq, const float* __restrict__ bk,
    const float* __restrict__ bv, ushort_t* __restrict__ embB,
    ushort_t* __restrict__ WB, float* __restrict__ bqkv,
    float* __restrict__ rowsum) {
  long gid = (long)blockIdx.x * blockDim.x + threadIdx.x;
  long stride = (long)gridDim.x * blockDim.x;
  const long tot4 = (N_EMB + 3 * N_W) >> 2;  // float4 count
  for (long i = gid; i < tot4; i += stride) {
    long e = i << 2;
    const float* src;
    ushort_t* dst;
    long off;
    if (e < N_EMB) {
      src = emb; dst = embB; off = e;
    } else {
      long wfl = e - N_EMB;
      int wi = (int)(wfl >> 20);          // /N_W
      off = wfl & (N_W - 1);
      src = wi == 0 ? Wq : (wi == 1 ? Wk : Wv);
      dst = WB + (long)wi * N_W;
    }
    float4 v = *(const float4*)(src + off);
    ushort4 o;
    o.x = f2b(v.x); o.y = f2b(v.y); o.z = f2b(v.z); o.w = f2b(v.w);
    *(ushort4*)(dst + off) = o;
  }
  if (blockIdx.x == 0) {
    for (int i = threadIdx.x; i < 1024; i += 256) {
      bqkv[i] = bq[i];
      bqkv[1024 + i] = bk[i];
      bqkv[2048 + i] = bv[i];
    }
  }
  if (blockIdx.x == 1) {
    for (int i = threadIdx.x; i < 8192; i += 256) rowsum[i] = 0.f;
  }
}

// ---------------- 128x128 GEMM body  C = A @ B^T  (A:[M][K], B:[N][K], bf16) ----------------
// BK=64, XOR-swizzled LDS; 32 MFMA per barrier; ~3 blocks/CU.
// MODE 0: projection. cols <2048 -> C bf16 = acc + bias into QKV; cols >=2048
//         (V third) -> transposed write into Vt[b][a][s] via LDS re-tile
//         (vectorized ds_write_b64: 4 consecutive transposed cols per write;
//         XOR swizzle only touches bits>=4 so the 8B chunk stays contiguous).
// MODE 1: P bf16 = exp(acc*scale) causal; rowsum atomics; packed-triangle grid
//         (136 = 8x17 bijective XCD-chunk swizzle).
// MODE 2: C f32 = acc / rowsum[row], K capped at (by+1)*BM; flip remap for
//         bz>=2 balances co-resident K-caps.
template <int MODE>
__device__ __forceinline__ void gemm_body(
    const ushort_t* __restrict__ A, const ushort_t* __restrict__ B,
    void* __restrict__ Cv, float* __restrict__ rowsum,
    int M, int N, int K, int lda, int ldb, int ldc,
    long bsA, long bsB, long bsC, float scale, ushort_t* __restrict__ VtOut) {
  int bx, by, bz = blockIdx.z;
  if (MODE == 1) {
    int sw = (blockIdx.x & 7) * 17 + (blockIdx.x >> 3);
    int r = (int)floorf((sqrtf(8.0f * sw + 1.0f) - 1.0f) * 0.5f);
    while ((r + 1) * (r + 2) / 2 <= sw) ++r;
    while (r * (r + 1) / 2 > sw) --r;
    by = r;
    bx = sw - r * (r + 1) / 2;     // bx <= by guaranteed
  } else if (MODE == 2) {
    bx = blockIdx.x;
    by = (bz & 2) ? ((int)gridDim.y - 1 - (int)blockIdx.y) : (int)blockIdx.y;
  } else {
    bx = blockIdx.x;
    by = blockIdx.y;
  }

  const ushort_t* Ab = A + (size_t)bz * bsA + (size_t)by * BM * lda;
  const ushort_t* Bb = B + (size_t)bz * bsB + (size_t)bx * BN * ldb;

  int Keff = K;
  if (MODE == 2) { int cap = (by + 1) * BM; Keff = cap < K ? cap : K; }

  __shared__ __align__(16) ushort_t sh[BM * BK + BN * BK];  // 32 KiB
  ushort_t* As = sh;
  ushort_t* Bs = sh + BM * BK;

  int tid = threadIdx.x;
  int lane = tid & 63;
  int w = tid >> 6;                 // 4 waves
  int wm = w >> 1, wn = w & 1;

  f32x4 acc[4][4];
#pragma unroll
  for (int i = 0; i < 4; i++)
#pragma unroll
    for (int j = 0; j < 4; j++) acc[i][j] = (f32x4)(0.f);

  // staging: wave w covers rows w*32 .. w*32+31 (4 gload_lds of 8 rows each)
  int srow = lane >> 3;                      // 0..7 within 8-row group
  int scol = ((lane & 7) ^ srow) << 3;       // pre-swizzled source col (elems)
  int fr = lane & 15, g16 = (lane >> 4) * 16;

  int nk = Keff / BK;
  for (int kt = 0; kt < nk; ++kt) {
    const ushort_t* Abase = Ab + (size_t)(w * 32 + srow) * lda + kt * BK + scol;
    const ushort_t* Bbase = Bb + (size_t)(w * 32 + srow) * ldb + kt * BK + scol;
#pragma unroll
    for (int j = 0; j < 4; ++j) {
      gload_lds16(Abase + (size_t)(j * 8) * lda, &As[(w * 32 + j * 8) * BK]);
      gload_lds16(Bbase + (size_t)(j * 8) * ldb, &Bs[(w * 32 + j * 8) * BK]);
    }
    __syncthreads();

    bf16x8 af[4][2], bf[4][2];
#pragma unroll
    for (int i = 0; i < 4; i++)
#pragma unroll
      for (int ks = 0; ks < 2; ++ks) {
        int ra = wm * 64 + i * 16 + fr;
        af[i][ks] = *(const bf16x8*)((const char*)As + ra * 128 +
                                     ((ks * 64 + g16) ^ ((ra & 7) << 4)));
        int rb2 = wn * 64 + i * 16 + fr;
        bf[i][ks] = *(const bf16x8*)((const char*)Bs + rb2 * 128 +
                                     ((ks * 64 + g16) ^ ((rb2 & 7) << 4)));
      }
#pragma unroll
    for (int mi = 0; mi < 4; mi++)
#pragma unroll
      for (int ni = 0; ni < 4; ni++)
#pragma unroll
        for (int ks = 0; ks < 2; ++ks)
          acc[mi][ni] = __builtin_amdgcn_mfma_f32_16x16x32_bf16(
              af[mi][ks], bf[ni][ks], acc[mi][ni], 0, 0, 0);
    __syncthreads();
  }

  int c = lane & 15;
  int rb = (lane >> 4) * 4;
  if (MODE == 0) {
    float bv4[4];
#pragma unroll
    for (int ni = 0; ni < 4; ni++) bv4[ni] = rowsum[bx * BN + wn * 64 + ni * 16 + c];
    if (bx < 16) {
      // Q|K thirds: normal row-major write into QKV
      ushort_t* Cp = (ushort_t*)Cv;
#pragma unroll
      for (int mi = 0; mi < 4; mi++)
#pragma unroll
        for (int j = 0; j < 4; j++) {
          int row = by * BM + wm * 64 + mi * 16 + rb + j;
#pragma unroll
          for (int ni = 0; ni < 4; ni++) {
            int col = bx * BN + wn * 64 + ni * 16 + c;
            Cp[(size_t)row * ldc + col] = f2b(acc[mi][ni][j] + bv4[ni]);
          }
        }
    } else {
      // V third: transpose via LDS, write Vt[b][a][s] coalesced.
      // vectorized: 4 consecutive transposed cols (j=0..3) = 8B chunk
      char* T = (char*)sh;
#pragma unroll
      for (int mi = 0; mi < 4; mi++) {
        int sl0 = wm * 64 + mi * 16 + rb;   // multiple of 4
#pragma unroll
        for (int ni = 0; ni < 4; ni++) {
          int al = wn * 64 + ni * 16 + c;
          ushort4 v4;
          v4.x = f2b(acc[mi][ni][0] + bv4[ni]);
          v4.y = f2b(acc[mi][ni][1] + bv4[ni]);
          v4.z = f2b(acc[mi][ni][2] + bv4[ni]);
          v4.w = f2b(acc[mi][ni][3] + bv4[ni]);
          *(ushort4*)(T + al * 256 + ((sl0 * 2) ^ ((al & 7) << 4))) = v4;
        }
      }
      __syncthreads();
      int b_ = by >> 4;                     // batch
      int s0 = (by & 15) * BM;              // seq offset within batch
      int a0 = (bx - 16) * BN;              // attn-dim offset
      ushort_t* Vb = VtOut + (size_t)b_ * 1024 * 2048;
#pragma unroll
      for (int p = 0; p < 16; ++p) {
        int al = (tid >> 5) + p * 8;
        int sl4 = (tid & 31) * 4;           // 4 ushorts = 8B per lane
        ushort4 v4 = *(const ushort4*)(T + al * 256 + ((sl4 * 2) ^ ((al & 7) << 4)));
        *(ushort4*)(Vb + (size_t)(a0 + al) * 2048 + s0 + sl4) = v4;
      }
    }
  } else if (MODE == 1) {
    ushort_t* Cp = (ushort_t*)Cv + (size_t)bz * bsC;
#pragma unroll
    for (int mi = 0; mi < 4; mi++)
#pragma unroll
      for (int j = 0; j < 4; j++) {
        int row = by * BM + wm * 64 + mi * 16 + rb + j;
        float rsum = 0.f;
#pragma unroll
        for (int ni = 0; ni < 4; ni++) {
          int col = bx * BN + wn * 64 + ni * 16 + c;
          float e = 0.f;
          if (bx != by || col <= row) e = __expf(acc[mi][ni][j] * scale);
          rsum += e;
          Cp[(size_t)row * ldc + col] = f2b(e);
        }
#pragma unroll
        for (int o = 1; o < 16; o <<= 1) rsum += __shfl_xor(rsum, o);
        if (c == 0) atomicAdd(&rowsum[(size_t)bz * M + row], rsum);
      }
  } else {
    float* C = (float*)Cv + (size_t)bz * bsC;
#pragma unroll
    for (int mi = 0; mi < 4; mi++)
#pragma unroll
      for (int j = 0; j < 4; j++) {
        int row = by * BM + wm * 64 + mi * 16 + rb + j;
        float inv = 1.0f / rowsum[(size_t)bz * M + row];
#pragma unroll
        for (int ni = 0; ni < 4; ni++) {
          int col = bx * BN + wn * 64 + ni * 16 + c;
          C[(size_t)row * ldc + col] = acc[mi][ni][j] * inv;
        }
      }
  }
}

// distinct kernel names so rocprof attributes each stage separately
__global__ __launch_bounds__(256, 3) void proj_qkv(
    const ushort_t* __restrict__ A, const ushort_t* __restrict__ B,
    void* __restrict__ Cv, float* __restrict__ bias,
    int M, int N, int K, int lda, int ldb, int ldc,
    long bsA, long bsB, long bsC, float scale, ushort_t* __restrict__ Vt) {
  gemm_body<0>(A, B, Cv, bias, M, N, K, lda, ldb, ldc, bsA, bsB, bsC, scale, Vt);
}

__global__ __launch_bounds__(256, 3) void score_causal(
    const ushort_t* __restrict__ A, const ushort_t* __restrict__ B,
    void* __restrict__ Cv, float* __restrict__ rowsum,
    int M, int N, int K, int lda, int ldb, int ldc,
    long bsA, long bsB, long bsC, float scale) {
  gemm_body<1>(A, B, Cv, rowsum, M, N, K, lda, ldb, ldc, bsA, bsB, bsC, scale, nullptr);
}

__global__ __launch_bounds__(256, 3) void pv_norm(
    const ushort_t* __restrict__ A, const ushort_t* __restrict__ B,
    void* __restrict__ Cv, float* __restrict__ rowsum,
    int M, int N, int K, int lda, int ldb, int ldc,
    long bsA, long bsB, long bsC, float scale) {
  gemm_body<2>(A, B, Cv, rowsum, M, N, K, lda, ldb, ldc, bsA, bsB, bsC, scale, nullptr);
}

extern "C" void kernel_launch(void* const* d_in, const int* in_sizes, int n_in,
                              void* d_out, int out_size, void* d_ws, size_t ws_size,
                              hipStream_t stream) {
  const int Bb = 4, S = 2048, E = 1024, A = 1024;
  const int N3 = 3 * A;             // fused projection width 3072
  const size_t M = (size_t)Bb * S;  // 8192
  const float* emb = (const float*)d_in[0];
  const float* Wq = (const float*)d_in[1];
  const float* bq = (const float*)d_in[2];
  const float* Wk = (const float*)d_in[3];
  const float* bk = (const float*)d_in[4];
  const float* Wv = (const float*)d_in[5];
  const float* bv = (const float*)d_in[6];
  float* out = (float*)d_out;

  char* ws = (char*)d_ws;
  // layout (byte offsets):
  ushort_t* QKV  = (ushort_t*)(ws + 0);           // 48 MiB [8192][3072]: Q|K|(V unused)
  ushort_t* Vt   = (ushort_t*)(ws + 50331648);    // 16 MiB [b][A][S]
  ushort_t* P    = (ushort_t*)(ws + 67108864);    // 32 MiB [b][S][S] bf16 (unnormalized exp)
  float* rowsum  = (float*)(ws + 100663296);      // 32 KiB [b*S]
  ushort_t* embB = (ushort_t*)(ws + 100696064);   // 16 MiB
  ushort_t* WB   = (ushort_t*)(ws + 117473280);   // 6 MiB = Wq|Wk|Wv bf16 [3072][1024]
  float*    bqkv = (float*)(ws + 123764736);      // 12 KiB
  if (ws_size < 157286400ull) return;             // refuse to corrupt

  // fused prep: emb+weights f32->bf16, bias concat, rowsum zero (1 node)
  prep_kernel<<<2048, 256, 0, stream>>>(emb, Wq, Wk, Wv, bq, bk, bv,
                                        embB, WB, bqkv, rowsum);

  // fused QKV projection (V third written transposed into Vt)
  proj_qkv<<<dim3(N3 / BN, M / BM, 1), dim3(256), 0, stream>>>(
      embB, WB, QKV, bqkv, (int)M, N3, E, E, E, N3, 0, 0, 0, 1.f, Vt);

  // scores: packed lower-triangle grid, 136 = 8*17 blocks per batch
  score_causal<<<dim3(136, 1, Bb), dim3(256), 0, stream>>>(
      QKV /*Q*/, QKV + A /*K*/, P, rowsum, S, S, E, N3, N3, S,
      (long)S * N3, (long)S * N3, (long)S * S, 0.03125f);

  // PV: per batch M=2048, N=1024, K=2048 (capped, flip-balanced), /rowsum
  pv_norm<<<dim3(A / BN, S / BM, Bb), dim3(256), 0, stream>>>(
      P, Vt, out, rowsum, S, A, S, S, S, A,
      (long)S * S, (long)A * S, (long)S * A, 1.f);
}